// Round 2
// baseline (260.940 us; speedup 1.0000x reference)
//
#include <hip/hip_runtime.h>
#include <hip/hip_bf16.h>

// difficultyWeightedLoss: mean over N of  w(t) * CE(logits[i], t[i]),  C=2.
// CE = logsumexp(l0,l1) - l_t = softplus(l_other - l_target).
// w = 1.4 if t==0 else 1.0.  text_keys (d_in[2]) unused by the reference.
//
// Single fused kernel: grid-stride streaming read (201 MB), block reduction,
// one fp32 atomicAdd per block into d_out (zeroed by a memset node — d_out is
// re-poisoned to 0xAA before every timed replay).
//
// Load pattern: per iteration each thread does two float4 logit loads offset
// by blockDim (consecutive lanes -> consecutive 16B, perfectly coalesced) and
// two int2 target loads (consecutive 8B). 48 B/thread/iter.

#define NBLK 2048
#define NTHR 256

__global__ __launch_bounds__(NTHR) void dwl_fused_kernel(
    const float* __restrict__ logits,   // (N,2) row-major
    const int* __restrict__ targets,    // (N,)
    float* __restrict__ out,            // (1,) pre-zeroed
    int n, float invN)
{
    const float4* lg4 = reinterpret_cast<const float4*>(logits);  // 2 samples per float4
    const int2*   tg2 = reinterpret_cast<const int2*>(targets);   // 2 samples per int2

    const int nPairs = n >> 1;                   // # of float4 / int2 elements
    const int base   = blockIdx.x * (2 * NTHR) + threadIdx.x;
    const int stride = NBLK * (2 * NTHR);

    float acc = 0.0f;

    for (int i0 = base; i0 < nPairs; i0 += stride) {
        const int i1 = i0 + NTHR;                // second coalesced slab

        const float4 a = lg4[i0];
        const int2   ta = tg2[i0];

        float4 b = make_float4(0.f, 0.f, 0.f, 0.f);
        int2   tb = make_int2(1, 1);             // weight 1, ce 0 -> contributes 0
        if (i1 < nPairs) { b = lg4[i1]; tb = tg2[i1]; }

        float l0[4] = {a.x, a.z, b.x, b.z};
        float l1[4] = {a.y, a.w, b.y, b.w};
        int   tt[4] = {ta.x, ta.y, tb.x, tb.y};

        #pragma unroll
        for (int k = 0; k < 4; ++k) {
            const bool one = (tt[k] == 1);
            const float lt = one ? l1[k] : l0[k];
            const float lo = one ? l0[k] : l1[k];
            const float d  = lo - lt;
            // stable softplus(d) = max(d,0) + log1p(exp(-|d|))
            const float ce = fmaxf(d, 0.0f) + __logf(1.0f + __expf(-fabsf(d)));
            acc += one ? ce : 1.4f * ce;
        }
    }

    // wave64 shuffle reduction
    #pragma unroll
    for (int off = 32; off > 0; off >>= 1)
        acc += __shfl_down(acc, off);

    __shared__ float smem[NTHR / 64];
    const int lane = threadIdx.x & 63;
    const int wave = threadIdx.x >> 6;
    if (lane == 0) smem[wave] = acc;
    __syncthreads();

    if (threadIdx.x == 0) {
        float blockSum = 0.0f;
        #pragma unroll
        for (int wv = 0; wv < NTHR / 64; ++wv) blockSum += smem[wv];
        atomicAdd(out, blockSum * invN);         // device-scope by default on CDNA
    }
}

extern "C" void kernel_launch(void* const* d_in, const int* in_sizes, int n_in,
                              void* d_out, int out_size, void* d_ws, size_t ws_size,
                              hipStream_t stream) {
    const float* logits  = (const float*)d_in[0];
    const int*   targets = (const int*)d_in[1];
    // d_in[2] (text_keys) unused by the reference — do not read it.

    const int n = in_sizes[1];           // N samples (in_sizes[0] == 2*N)
    float* out = (float*)d_out;

    hipMemsetAsync(out, 0, sizeof(float), stream);   // graph-capturable memset node
    dwl_fused_kernel<<<NBLK, NTHR, 0, stream>>>(logits, targets, out, n,
                                                (float)(1.0 / (double)n));
}